// Round 2
// baseline (177.977 us; speedup 1.0000x reference)
//
#include <hip/hip_runtime.h>

#define NB 4
#define NC 6
#define NF 257
#define NT 2000
#define NG (NB * NF)        // 1028 (b,f) groups
#define NPAIR 15
#define NACC 74             // [0..5] s_diag, [6..11] n_diag, [12+4p..] s_re,s_im,n_re,n_im, [72] sum_ms, [73] sum_mn
#define NCHUNK 2
#define TCH (NT / NCHUNK)   // 1000 t per chunk
#define BLK 256
#define CS  (NF * NT)       // channel stride (floats)
#define CS2 (CS / 2)        // channel stride (float2)

__device__ __forceinline__ void acc_pos(
    const float2* __restrict__ s2r, const float2* __restrict__ s2i,
    const float2* __restrict__ m2s, const float2* __restrict__ m2n,
    int p, float (&acc)[NACC])
{
    constexpr int PC[NPAIR] = {0,0,0,0,0,1,1,1,1,2,2,2,3,3,4};
    constexpr int PE[NPAIR] = {1,2,3,4,5,2,3,4,5,3,4,5,4,5,5};

    const float2 vms = m2s[p];
    const float2 vmn = m2n[p];
    acc[72] += vms.x + vms.y;
    acc[73] += vmn.x + vmn.y;

    float2 re[NC], im[NC];
    #pragma unroll
    for (int c = 0; c < NC; c++) {
        re[c] = s2r[c * CS2 + p];
        im[c] = s2i[c * CS2 + p];
    }
    #pragma unroll
    for (int c = 0; c < NC; c++) {
        const float d0 = re[c].x * re[c].x + im[c].x * im[c].x;
        const float d1 = re[c].y * re[c].y + im[c].y * im[c].y;
        acc[c]     += d0 * vms.x + d1 * vms.y;
        acc[6 + c] += d0 * vmn.x + d1 * vmn.y;
    }
    #pragma unroll
    for (int q = 0; q < NPAIR; q++) {
        const int c = PC[q], e = PE[q];
        const float cr0 = re[c].x * re[e].x + im[c].x * im[e].x;
        const float ci0 = im[c].x * re[e].x - re[c].x * im[e].x;
        const float cr1 = re[c].y * re[e].y + im[c].y * im[e].y;
        const float ci1 = im[c].y * re[e].y - re[c].y * im[e].y;
        acc[12 + 4 * q + 0] += cr0 * vms.x + cr1 * vms.y;
        acc[12 + 4 * q + 1] += ci0 * vms.x + ci1 * vms.y;
        acc[12 + 4 * q + 2] += cr0 * vmn.x + cr1 * vmn.y;
        acc[12 + 4 * q + 3] += ci0 * vmn.x + ci1 * vmn.y;
    }
}

// ---------------- Kernel A: raw weighted PSD partials per (group, chunk) ----
__global__ __launch_bounds__(BLK) void psd_kernel(
    const float* __restrict__ sr, const float* __restrict__ si,
    const float* __restrict__ ms, const float* __restrict__ mn,
    float* __restrict__ wsp)
{
    const int bx = blockIdx.x;
    const int g  = bx >> 1;
    const int b  = g / NF;
    const int f  = g - b * NF;
    const int tb = (bx & 1) * TCH;
    const int sbase = b * NC * CS + f * NT + tb;
    const int mbase = g * NT + tb;

    const float2* s2r = (const float2*)(sr + sbase);
    const float2* s2i = (const float2*)(si + sbase);
    const float2* m2s = (const float2*)(ms + mbase);
    const float2* m2n = (const float2*)(mn + mbase);

    float acc[NACC];
    #pragma unroll
    for (int i = 0; i < NACC; i++) acc[i] = 0.f;

    acc_pos(s2r, s2i, m2s, m2n, threadIdx.x, acc);                // p in [0,256)
    if (threadIdx.x < (TCH / 2 - BLK))                            // p in [256,500)
        acc_pos(s2r, s2i, m2s, m2n, threadIdx.x + BLK, acc);

    // 3-stage shuffle: lane l<8 holds sum over lanes {l, l+8, ..., l+56}
    #pragma unroll
    for (int i = 0; i < NACC; i++) {
        float v = acc[i];
        v += __shfl_down(v, 32);
        v += __shfl_down(v, 16);
        v += __shfl_down(v, 8);
        acc[i] = v;
    }

    __shared__ float red[32][NACC];
    const int wid  = threadIdx.x >> 6;
    const int lane = threadIdx.x & 63;
    if (lane < 8) {
        #pragma unroll
        for (int i = 0; i < NACC; i++) red[wid * 8 + lane][i] = acc[i];
    }
    __syncthreads();

    if (threadIdx.x < NACC) {
        float s = 0.f;
        #pragma unroll
        for (int r = 0; r < 32; r++) s += red[r][threadIdx.x];
        wsp[bx * NACC + threadIdx.x] = s;
    }
}

// ---------------- Kernel B: one thread per (b,f) — combine + 6x6 solve ------
__global__ void solve_kernel(const float* __restrict__ wsp, float* __restrict__ wsw)
{
    const int gid = blockIdx.x * 64 + threadIdx.x;
    if (gid >= NG) return;

    constexpr int PC[NPAIR] = {0,0,0,0,0,1,1,1,1,2,2,2,3,3,4};
    constexpr int PE[NPAIR] = {1,2,3,4,5,2,3,4,5,3,4,5,4,5,5};

    const float* p0 = wsp + (2 * gid) * NACC;
    const float* p1 = p0 + NACC;
    float fin[NACC];
    #pragma unroll
    for (int i = 0; i < NACC; i++) fin[i] = p0[i] + p1[i];

    const float invS = 1.f / (fin[72] + 1e-15f);
    const float invN = 1.f / (fin[73] + 1e-15f);

    float Ar[NC][NC], Ai[NC][NC], Br[NC][NC], Bi[NC][NC];
    #pragma unroll
    for (int c = 0; c < NC; c++) {
        Br[c][c] = fin[c] * invS;     Bi[c][c] = 0.f;
        Ar[c][c] = fin[6 + c] * invN; Ai[c][c] = 0.f;
    }
    #pragma unroll
    for (int q = 0; q < NPAIR; q++) {
        const int c = PC[q], e = PE[q];
        const float sre = fin[12 + 4 * q + 0] * invS;
        const float sim = fin[12 + 4 * q + 1] * invS;
        const float nre = fin[12 + 4 * q + 2] * invN;
        const float nim = fin[12 + 4 * q + 3] * invN;
        Br[c][e] = sre;  Bi[c][e] = sim;
        Br[e][c] = sre;  Bi[e][c] = -sim;
        Ar[c][e] = nre;  Ai[c][e] = nim;
        Ar[e][c] = nre;  Ai[e][c] = -nim;
    }

    float trn = 0.f;
    #pragma unroll
    for (int c = 0; c < NC; c++) trn += Ar[c][c];
    const float eps = trn * 1e-7f + 1e-8f;
    #pragma unroll
    for (int c = 0; c < NC; c++) Ar[c][c] += eps;

    // Forward elimination (no pivoting: A is HPD)
    #pragma unroll
    for (int k = 0; k < NC; k++) {
        const float dr = Ar[k][k], di = Ai[k][k];
        const float idn = 1.f / (dr * dr + di * di);
        const float pr = dr * idn, pi = -di * idn;
        #pragma unroll
        for (int i2 = k + 1; i2 < NC; i2++) {
            const float fr = Ar[i2][k] * pr - Ai[i2][k] * pi;
            const float fi = Ar[i2][k] * pi + Ai[i2][k] * pr;
            #pragma unroll
            for (int j = k + 1; j < NC; j++) {
                Ar[i2][j] -= fr * Ar[k][j] - fi * Ai[k][j];
                Ai[i2][j] -= fr * Ai[k][j] + fi * Ar[k][j];
            }
            #pragma unroll
            for (int j = 0; j < NC; j++) {
                Br[i2][j] -= fr * Br[k][j] - fi * Bi[k][j];
                Bi[i2][j] -= fr * Bi[k][j] + fi * Br[k][j];
            }
        }
    }
    // Back substitution, in place into B (B becomes X)
    #pragma unroll
    for (int k = NC - 1; k >= 0; k--) {
        const float dr = Ar[k][k], di = Ai[k][k];
        const float idn = 1.f / (dr * dr + di * di);
        const float pr = dr * idn, pi = -di * idn;
        #pragma unroll
        for (int j = 0; j < NC; j++) {
            float xr = Br[k][j], xi = Bi[k][j];
            #pragma unroll
            for (int m = k + 1; m < NC; m++) {
                xr -= Ar[k][m] * Br[m][j] - Ai[k][m] * Bi[m][j];
                xi -= Ar[k][m] * Bi[m][j] + Ai[k][m] * Br[m][j];
            }
            Br[k][j] = xr * pr - xi * pi;
            Bi[k][j] = xr * pi + xi * pr;
        }
    }

    float trr = 1e-8f, tri = 0.f;   // TIK_EPS on real part of trace
    #pragma unroll
    for (int c = 0; c < NC; c++) { trr += Br[c][c]; tri += Bi[c][c]; }
    const float idn = 1.f / (trr * trr + tri * tri);
    #pragma unroll
    for (int c = 0; c < NC; c++) {
        const float xr = Br[c][0], xi = Bi[c][0];
        const float wre = (xr * trr + xi * tri) * idn;
        const float wim = (xi * trr - xr * tri) * idn;
        wsw[gid * 12 + c]     = wre;    // conj(w): real
        wsw[gid * 12 + 6 + c] = -wim;   // conj(w): imag
    }
}

// ---------------- Kernel C: enh[t] = sum_c conj(w[c]) * spec[c,t] -----------
__global__ __launch_bounds__(BLK) void apply_kernel(
    const float* __restrict__ sr, const float* __restrict__ si,
    const float* __restrict__ wsw, float* __restrict__ out)
{
    const int bx = blockIdx.x;
    const int g  = bx >> 1;
    const int b  = g / NF;
    const int f  = g - b * NF;
    const int tb = (bx & 1) * TCH;
    const int sbase = b * NC * CS + f * NT + tb;

    const float2* s2r = (const float2*)(sr + sbase);
    const float2* s2i = (const float2*)(si + sbase);

    float wr[NC], wi[NC];
    #pragma unroll
    for (int c = 0; c < NC; c++) {
        wr[c] = wsw[g * 12 + c];
        wi[c] = wsw[g * 12 + 6 + c];
    }

    float4* o4 = (float4*)out + (g * NT + tb) / 2;

    {
        const int p = threadIdx.x;
        float er0 = 0.f, ei0 = 0.f, er1 = 0.f, ei1 = 0.f;
        #pragma unroll
        for (int c = 0; c < NC; c++) {
            const float2 a  = s2r[c * CS2 + p];
            const float2 bb = s2i[c * CS2 + p];
            er0 += wr[c] * a.x - wi[c] * bb.x;
            ei0 += wr[c] * bb.x + wi[c] * a.x;
            er1 += wr[c] * a.y - wi[c] * bb.y;
            ei1 += wr[c] * bb.y + wi[c] * a.y;
        }
        o4[p] = make_float4(er0, ei0, er1, ei1);
    }
    if (threadIdx.x < (TCH / 2 - BLK)) {
        const int p = threadIdx.x + BLK;
        float er0 = 0.f, ei0 = 0.f, er1 = 0.f, ei1 = 0.f;
        #pragma unroll
        for (int c = 0; c < NC; c++) {
            const float2 a  = s2r[c * CS2 + p];
            const float2 bb = s2i[c * CS2 + p];
            er0 += wr[c] * a.x - wi[c] * bb.x;
            ei0 += wr[c] * bb.x + wi[c] * a.x;
            er1 += wr[c] * a.y - wi[c] * bb.y;
            ei1 += wr[c] * bb.y + wi[c] * a.y;
        }
        o4[p] = make_float4(er0, ei0, er1, ei1);
    }
}

extern "C" void kernel_launch(void* const* d_in, const int* in_sizes, int n_in,
                              void* d_out, int out_size, void* d_ws, size_t ws_size,
                              hipStream_t stream) {
    const float* sr = (const float*)d_in[0];
    const float* si = (const float*)d_in[1];
    const float* ms = (const float*)d_in[2];
    const float* mn = (const float*)d_in[3];
    float* out = (float*)d_out;

    float* wsp = (float*)d_ws;                       // [NG*NCHUNK][NACC] partials
    float* wsw = wsp + NG * NCHUNK * NACC;           // [NG][12] conj(w)

    psd_kernel<<<NG * NCHUNK, BLK, 0, stream>>>(sr, si, ms, mn, wsp);
    solve_kernel<<<(NG + 63) / 64, 64, 0, stream>>>(wsp, wsw);
    apply_kernel<<<NG * NCHUNK, BLK, 0, stream>>>(sr, si, wsw, out);
}